// Round 13
// baseline (354.923 us; speedup 1.0000x reference)
//
#include <hip/hip_runtime.h>
#include <hip/hip_bf16.h>

// Problem constants
#define BB 2
#define SS 2048
#define DD 1024
#define HH 16
#define DP 64

typedef __bf16 bf16x8 __attribute__((ext_vector_type(8)));
typedef float f32x4 __attribute__((ext_vector_type(4)));

__device__ __forceinline__ unsigned short f2bf(float f) {
  unsigned u = __float_as_uint(f);
  unsigned r = u + 0x7FFFu + ((u >> 16) & 1u);
  return (unsigned short)(r >> 16);
}

__device__ __forceinline__ bf16x8 load8(const unsigned short* p) {
  return __builtin_bit_cast(bf16x8, *(const uint4*)p);
}

__device__ __forceinline__ f32x4 mfma16(bf16x8 a, bf16x8 b, f32x4 c) {
  return __builtin_amdgcn_mfma_f32_16x16x32_bf16(a, b, c, 0, 0, 0);
}

// ---------------- prep: transpose+convert weights, pack mask bits ----------
__global__ __launch_bounds__(256) void imha_prep(
    const float* __restrict__ Wq, const float* __restrict__ Wk,
    const float* __restrict__ Wo, const float* __restrict__ Wv,
    const int* __restrict__ mask,
    unsigned short* __restrict__ wqt, unsigned short* __restrict__ wkt,
    unsigned short* __restrict__ wot, unsigned short* __restrict__ wvt,
    unsigned* __restrict__ mb) {
  const int bx = blockIdx.x, t = threadIdx.x;
  if (bx < 2048) {
    const float* src = (bx < 1024) ? Wq : Wk;
    unsigned short* dst = (bx < 1024) ? wqt : wkt;
    const int tile = bx & 1023;
    const int ty = tile >> 5, tx = tile & 31;
    __shared__ float T[32][33];
    const int r = t >> 3, c4 = (t & 7) * 4;
    const float4 v = *(const float4*)&src[(ty * 32 + r) * 1024 + tx * 32 + c4];
    T[r][c4 + 0] = v.x; T[r][c4 + 1] = v.y; T[r][c4 + 2] = v.z; T[r][c4 + 3] = v.w;
    __syncthreads();
    ushort4 o;
    o.x = f2bf(T[c4 + 0][r]); o.y = f2bf(T[c4 + 1][r]);
    o.z = f2bf(T[c4 + 2][r]); o.w = f2bf(T[c4 + 3][r]);
    *(ushort4*)&dst[(tx * 32 + r) * 1024 + ty * 32 + c4] = o;
  } else if (bx < 2304) {
    const int idx = (bx - 2048) * 256 + t;
    const int n = idx >> 6, k = idx & 63;
    wot[idx] = f2bf(Wo[k * 1024 + n]);
  } else if (bx < 2816) {
    const int widx = (bx - 2304) * 256 + t;  // 131072 words
    const int qr = widx >> 6, wd = widx & 63;
    const int* mrow = mask + qr * 2048 + wd * 32;
    unsigned wv = 0;
    #pragma unroll
    for (int j4 = 0; j4 < 8; ++j4) {
      const int4 m4 = *(const int4*)&mrow[j4 * 4];
      wv |= (unsigned)(m4.x & 1) << (j4 * 4);
      wv |= (unsigned)(m4.y & 1) << (j4 * 4 + 1);
      wv |= (unsigned)(m4.z & 1) << (j4 * 4 + 2);
      wv |= (unsigned)(m4.w & 1) << (j4 * 4 + 3);
    }
    mb[widx] = wv;
  } else {
    const int widx = (bx - 2816) * 256 + t;  // 65536
    const int k = widx >> 6, n = widx & 63;
    wvt[n * 1024 + k] = f2bf(Wv[widx]);
  }
}

// ---------------- projection GEMM (BM=64, BN=128) --------------------------
__global__ __launch_bounds__(256) void imha_proj(
    const float* __restrict__ X, const unsigned short* __restrict__ Wt,
    const float* __restrict__ bias, unsigned short* __restrict__ dst,
    float preScale) {
  __shared__ unsigned short As[64][40];
  __shared__ unsigned short Bs[128][40];
  const int t = threadIdx.x, l = t & 63, w = t >> 6, lr = l & 15, lg = l >> 4;
  const int m0 = blockIdx.x * 64, n0 = blockIdx.y * 128;
  const int wr = w >> 1, wc = w & 1;
  const f32x4 zf = {0.f, 0.f, 0.f, 0.f};
  f32x4 acc[2][4];
  #pragma unroll
  for (int i = 0; i < 2; ++i)
    #pragma unroll
    for (int j = 0; j < 4; ++j) acc[i][j] = zf;

  for (int kk = 0; kk < 32; ++kk) {
    {
      const int rA = t >> 2, cA = (t & 3) * 8;
      const float4 v0 = *(const float4*)&X[(m0 + rA) * 1024 + kk * 32 + cA];
      const float4 v1 = *(const float4*)&X[(m0 + rA) * 1024 + kk * 32 + cA + 4];
      ushort4 o0, o1;
      o0.x = f2bf(v0.x); o0.y = f2bf(v0.y); o0.z = f2bf(v0.z); o0.w = f2bf(v0.w);
      o1.x = f2bf(v1.x); o1.y = f2bf(v1.y); o1.z = f2bf(v1.z); o1.w = f2bf(v1.w);
      *(ushort4*)&As[rA][cA] = o0;
      *(ushort4*)&As[rA][cA + 4] = o1;
      const int rB = t >> 2, cB = (t & 3) * 8;
      #pragma unroll
      for (int p = 0; p < 2; ++p) {
        const uint4 u = *(const uint4*)&Wt[(n0 + p * 64 + rB) * 1024 + kk * 32 + cB];
        *(uint4*)&Bs[p * 64 + rB][cB] = u;
      }
    }
    __syncthreads();
    bf16x8 a[2], bf[4];
    #pragma unroll
    for (int i = 0; i < 2; ++i) a[i] = load8(&As[wr * 32 + i * 16 + lr][lg * 8]);
    #pragma unroll
    for (int j = 0; j < 4; ++j) bf[j] = load8(&Bs[wc * 64 + j * 16 + lr][lg * 8]);
    #pragma unroll
    for (int i = 0; i < 2; ++i)
      #pragma unroll
      for (int j = 0; j < 4; ++j) acc[i][j] = mfma16(a[i], bf[j], acc[i][j]);
    __syncthreads();
  }
  #pragma unroll
  for (int j = 0; j < 4; ++j) {
    const int gn = n0 + wc * 64 + j * 16 + lr;
    const float bv = bias[gn];
    const int h = gn >> 6, d = gn & 63;
    #pragma unroll
    for (int i = 0; i < 2; ++i) {
      #pragma unroll
      for (int r = 0; r < 4; ++r) {
        const int gm = m0 + wr * 32 + i * 16 + lg * 4 + r;
        const int b = gm >> 11, s = gm & 2047;
        dst[(((b * 16 + h) * 2048 + s) << 6) + d] = f2bf((acc[i][j][r] + bv) * preScale);
      }
    }
  }
}

// ---------------- V projection (MFMA, K-split): partials -------------------
__global__ __launch_bounds__(256) void imha_vproj_mm(
    const float* __restrict__ V, const unsigned short* __restrict__ wvt,
    float* __restrict__ ctxvp) {
  const int t = threadIdx.x, l = t & 63, w = t >> 6, lr = l & 15, lg = l >> 4;
  const int m0 = blockIdx.x * 64 + w * 16;
  const int k0 = blockIdx.y * 128;
  const f32x4 zf = {0.f, 0.f, 0.f, 0.f};
  f32x4 acc[4];
  #pragma unroll
  for (int j = 0; j < 4; ++j) acc[j] = zf;
  #pragma unroll
  for (int kk = 0; kk < 4; ++kk) {
    const int kb = k0 + kk * 32 + lg * 8;
    const float4 v0 = *(const float4*)&V[(m0 + lr) * 1024 + kb];
    const float4 v1 = *(const float4*)&V[(m0 + lr) * 1024 + kb + 4];
    union { bf16x8 v; unsigned short u[8]; } au;
    au.u[0] = f2bf(v0.x); au.u[1] = f2bf(v0.y); au.u[2] = f2bf(v0.z); au.u[3] = f2bf(v0.w);
    au.u[4] = f2bf(v1.x); au.u[5] = f2bf(v1.y); au.u[6] = f2bf(v1.z); au.u[7] = f2bf(v1.w);
    #pragma unroll
    for (int j = 0; j < 4; ++j) {
      const bf16x8 bfr = load8(&wvt[(j * 16 + lr) * 1024 + kb]);
      acc[j] = mfma16(au.v, bfr, acc[j]);
    }
  }
  #pragma unroll
  for (int j = 0; j < 4; ++j)
    #pragma unroll
    for (int reg = 0; reg < 4; ++reg) {
      const int m = m0 + lg * 4 + reg;
      ctxvp[((size_t)blockIdx.y * 4096 + m) * 64 + j * 16 + lr] = acc[j][reg];
    }
}

// ---------------- reduce partials -> vpT[b,d,s] bf16 -----------------------
__global__ __launch_bounds__(256) void imha_vred(
    const float* __restrict__ ctxvp, const float* __restrict__ bv,
    unsigned short* __restrict__ vpt) {
  __shared__ float T[128][65];
  const int t = threadIdx.x;
  const int m0 = blockIdx.x * 128;  // 32 blocks
  #pragma unroll
  for (int i = 0; i < 32; ++i) {
    const int e = t + i * 256;
    float s = 0.f;
    #pragma unroll
    for (int p = 0; p < 8; ++p) s += ctxvp[(size_t)p * 262144 + (size_t)m0 * 64 + e];
    T[e >> 6][e & 63] = s;
  }
  __syncthreads();
  const int d = t >> 2, sc = (t & 3) * 32;
  const int b = m0 >> 11, srow = m0 & 2047;
  const float bias = bv[d];
  unsigned short* dst = vpt + ((size_t)b * 64 + d) * 2048 + srow + sc;
  #pragma unroll
  for (int i = 0; i < 32; i += 8) {
    ushort4 o0, o1;
    o0.x = f2bf(T[sc + i + 0][d] + bias); o0.y = f2bf(T[sc + i + 1][d] + bias);
    o0.z = f2bf(T[sc + i + 2][d] + bias); o0.w = f2bf(T[sc + i + 3][d] + bias);
    o1.x = f2bf(T[sc + i + 4][d] + bias); o1.y = f2bf(T[sc + i + 5][d] + bias);
    o1.z = f2bf(T[sc + i + 6][d] + bias); o1.w = f2bf(T[sc + i + 7][d] + bias);
    *(ushort4*)(dst + i) = o0;
    *(ushort4*)(dst + i + 4) = o1;
  }
}

// ---------------- pass1 (h-major): 2 K-tiles (32KB) per barrier ------------
// 512 blocks (XCD-swizzled): block = (q-tile 128, b*16+h); 8 staging rounds.
__global__ __launch_bounds__(256, 3) void imha_pass1(
    const unsigned short* __restrict__ qhb, const unsigned short* __restrict__ khb,
    const unsigned* __restrict__ mb, float* __restrict__ lpart16) {
  __shared__ unsigned short Kb[2][16384];  // 2 x (2 x 128x64) bf16, XOR-swizzled
  const int t = threadIdx.x, l = t & 63, w = t >> 6, lr = l & 15, lg = l >> 4;
  const int orig = blockIdx.x;                       // 512
  const int swz = (orig & 7) * 64 + (orig >> 3);     // XCD-chunked
  const int q0 = (swz & 15) * 128, bh = swz >> 4;
  const int qw = q0 + w * 32;
  // hoisted Q fragments
  const unsigned short* qb = qhb + ((size_t)(bh * 2048 + qw) << 6);
  bf16x8 aq[2][2];
  #pragma unroll
  for (int rf = 0; rf < 2; ++rf)
    #pragma unroll
    for (int k2 = 0; k2 < 2; ++k2)
      aq[rf][k2] = load8(qb + (((rf * 16 + lr) << 6) + k2 * 32 + lg * 8));
  const unsigned short* kbase = khb + ((size_t)bh << 17);  // bh*2048*64
  uint4 pre[8];
  // prologue: stage tiles 0,1 (32KB)
  #pragma unroll
  for (int it = 0; it < 8; ++it)
    pre[it] = *(const uint4*)((const char*)kbase + (it * 256 + t) * 16);
  #pragma unroll
  for (int it = 0; it < 8; ++it) {
    const int off = (it * 256 + t) * 16;
    const int sub = off >> 14, ro = (off & 16383) >> 7, col = off & 127;
    *(uint4*)((char*)&Kb[0][0] + sub * 16384 + ro * 128 + (col ^ ((ro & 7) << 4))) = pre[it];
  }
  __syncthreads();
  float lsum[2][4] = {0.f, 0.f, 0.f, 0.f, 0.f, 0.f, 0.f, 0.f};
  #pragma unroll 1
  for (int KT = 0; KT < 8; ++KT) {
    if (KT < 7) {
      const char* nk = (const char*)kbase + (KT + 1) * 32768;
      #pragma unroll
      for (int it = 0; it < 8; ++it)
        pre[it] = *(const uint4*)(nk + (it * 256 + t) * 16);
    }
    const int sxor = (lr & 7) << 4;
    __builtin_amdgcn_s_setprio(1);
    #pragma unroll
    for (int sub = 0; sub < 2; ++sub) {
      const int kt = KT * 2 + sub;
      uint4 mw[2][4];
      #pragma unroll
      for (int rf = 0; rf < 2; ++rf)
        #pragma unroll
        for (int reg = 0; reg < 4; ++reg) {
          const int qrow = qw + rf * 16 + lg * 4 + reg;
          mw[rf][reg] = *(const uint4*)&mb[qrow * 64 + kt * 4];
        }
      const char* kl = (const char*)&Kb[KT & 1][0] + sub * 16384;
      #pragma unroll
      for (int cf = 0; cf < 8; ++cf) {
        const int row = cf * 16 + lr;
        const bf16x8 b0 = load8((const unsigned short*)(kl + row * 128 + ((lg * 16) ^ sxor)));
        const bf16x8 b1 = load8((const unsigned short*)(kl + row * 128 + ((64 + lg * 16) ^ sxor)));
        #pragma unroll
        for (int rf = 0; rf < 2; ++rf) {
          f32x4 aini;
          #pragma unroll
          for (int reg = 0; reg < 4; ++reg) {
            const unsigned word = ((const unsigned*)&mw[rf][reg])[cf >> 1];
            const unsigned bit = (word >> (((cf & 1) << 4) + lr)) & 1u;
            aini[reg] = bit ? -30000.0f : 0.0f;
          }
          f32x4 acc = mfma16(aq[rf][0], b0, aini);
          acc = mfma16(aq[rf][1], b1, acc);
          #pragma unroll
          for (int reg = 0; reg < 4; ++reg)
            lsum[rf][reg] += __builtin_exp2f(acc[reg]);
        }
      }
    }
    __builtin_amdgcn_s_setprio(0);
    if (KT < 7) {
      #pragma unroll
      for (int it = 0; it < 8; ++it) {
        const int off = (it * 256 + t) * 16;
        const int sub = off >> 14, ro = (off & 16383) >> 7, col = off & 127;
        *(uint4*)((char*)&Kb[(KT + 1) & 1][0] + sub * 16384 + ro * 128 + (col ^ ((ro & 7) << 4))) = pre[it];
      }
      __syncthreads();
    }
  }
  // unreduced 16-lane partials: lpart16[(bh*2048+q)*16 + lr]
  #pragma unroll
  for (int rf = 0; rf < 2; ++rf)
    #pragma unroll
    for (int reg = 0; reg < 4; ++reg) {
      const int qrow = bh * 2048 + qw + rf * 16 + lg * 4 + reg;
      lpart16[(qrow << 4) + lr] = lsum[rf][reg];
    }
}

// ---------------- linv = (1/16) / sum(lpart16) -----------------------------
__global__ __launch_bounds__(256) void imha_linv(
    const float* __restrict__ lpart16, float* __restrict__ linv) {
  const int i = blockIdx.x * 256 + threadIdx.x;  // 65536
  const float4* p = (const float4*)&lpart16[i << 4];
  float s = 0.f;
  #pragma unroll
  for (int j = 0; j < 4; ++j) {
    const float4 v = p[j];
    s += v.x + v.y + v.z + v.w;
  }
  linv[i] = 0.0625f / s;
}

// ---------------- pass2: 2 heads' K-tiles per barrier, Ps unioned ----------
// 512 blocks (XCD-swizzled): q-tile 128 (4 waves x 32q), k-tile 128, 8 rounds
__global__ __launch_bounds__(256, 2) void imha_pass2(
    const unsigned short* __restrict__ qhb, const unsigned short* __restrict__ khb,
    const unsigned short* __restrict__ vpt, const unsigned* __restrict__ mb,
    const float* __restrict__ linv, float* __restrict__ attn_out,
    float* __restrict__ ctxp) {
  // union: Kb[2][32KB] (h-loop) | Ps[128][136] shorts (34 KB, epilogue)
  __shared__ char smem[65536];
  unsigned short (*Kb)[16384] = (unsigned short(*)[16384])smem;
  unsigned short (*Ps)[136] = (unsigned short(*)[136])smem;
  const int t = threadIdx.x, l = t & 63, w = t >> 6, lr = l & 15, lg = l >> 4;
  const int orig = blockIdx.x;                    // 512
  const int swz = (orig & 7) * 64 + (orig >> 3);  // XCD-chunked
  const int q0 = (swz & 15) * 128, ksb = (swz >> 4) & 15, b = swz >> 8;
  const int k00 = ksb * 128;
  const int qw = q0 + w * 32;
  f32x4 aini[2][2][4];
  #pragma unroll
  for (int rf = 0; rf < 2; ++rf)
    #pragma unroll
    for (int reg = 0; reg < 4; ++reg) {
      const int qrow = qw + rf * 16 + lg * 4 + reg;
      const unsigned* mrow = mb + qrow * 64;
      #pragma unroll
      for (int kt = 0; kt < 2; ++kt)
        #pragma unroll
        for (int cf = 0; cf < 4; ++cf) {
          const unsigned word = mrow[(k00 + kt * 64 + cf * 16) >> 5];
          const unsigned bit = (word >> (((cf & 1) << 4) + lr)) & 1u;
          aini[rf][kt][cf][reg] = bit ? -30000.0f : 0.0f;
        }
    }
  float pm[2][2][4][4];
  #pragma unroll
  for (int a = 0; a < 2; ++a)
    #pragma unroll
    for (int c = 0; c < 2; ++c)
      #pragma unroll
      for (int d2 = 0; d2 < 4; ++d2)
        #pragma unroll
        for (int e = 0; e < 4; ++e) pm[a][c][d2][e] = 0.f;

  const unsigned short* kbase = khb + ((size_t)((b * 16) * 2048 + k00) << 6);
  uint4 pre[8];
  // prologue: stage heads 0,1
  #pragma unroll
  for (int it = 0; it < 8; ++it) {
    const char* hb = (const char*)(kbase + ((size_t)(it >> 2) << 17));
    pre[it] = *(const uint4*)(hb + (((it & 3) * 256 + t) * 16));
  }
  #pragma unroll
  for (int it = 0; it < 8; ++it) {
    const int sub = it >> 2, off = ((it & 3) * 256 + t) * 16;
    const int ro = off >> 7, col = off & 127;
    *(uint4*)((char*)&Kb[0][0] + sub * 16384 + ro * 128 + (col ^ ((ro & 7) << 4))) = pre[it];
  }
  __syncthreads();
  #pragma unroll 1
  for (int H2 = 0; H2 < 8; ++H2) {
    if (H2 < 7) {
      #pragma unroll
      for (int it = 0; it < 8; ++it) {
        const char* hb = (const char*)(kbase + ((size_t)(H2 * 2 + 2 + (it >> 2)) << 17));
        pre[it] = *(const uint4*)(hb + (((it & 3) * 256 + t) * 16));
      }
    }
    const int sxor = (lr & 7) << 4;
    __builtin_amdgcn_s_setprio(1);
    #pragma unroll
    for (int sub = 0; sub < 2; ++sub) {
      const int h = H2 * 2 + sub;
      const unsigned short* qb = qhb + ((size_t)((b * 16 + h) * 2048 + qw) << 6);
      bf16x8 aq[2][2];
      #pragma unroll
      for (int rf = 0; rf < 2; ++rf)
        #pragma unroll
        for (int k2 = 0; k2 < 2; ++k2)
          aq[rf][k2] = load8(qb + (((rf * 16 + lr) << 6) + k2 * 32 + lg * 8));
      float4 li4[2];
      #pragma unroll
      for (int rf = 0; rf < 2; ++rf)
        li4[rf] = *(const float4*)&linv[(b * 16 + h) * 2048 + qw + rf * 16 + lg * 4];
      const char* kl = (const char*)&Kb[H2 & 1][0] + sub * 16384;
      #pragma unroll
      for (int kt = 0; kt < 2; ++kt) {
        #pragma unroll
        for (int cf = 0; cf < 4; ++cf) {
          const int row = kt * 64 + cf * 16 + lr;
          const bf16x8 b0 = load8((const unsigned short*)(kl + row * 128 + ((lg * 16) ^ sxor)));
          const bf16x8 b1 = load8((const unsigned short*)(kl + row * 128 + ((64 + lg * 16) ^ sxor)));
          #pragma unroll
          for (int rf = 0; rf < 2; ++rf) {
            f32x4 acc = mfma16(aq[rf][0], b0, aini[rf][kt][cf]);
            acc = mfma16(aq[rf][1], b1, acc);
            const float* lip = (const float*)&li4[rf];
            #pragma unroll
            for (int reg = 0; reg < 4; ++reg)
              pm[rf][kt][cf][reg] += __builtin_exp2f(acc[reg]) * lip[reg];
          }
        }
      }
    }
    __builtin_amdgcn_s_setprio(0);
    if (H2 < 7) {
      #pragma unroll
      for (int it = 0; it < 8; ++it) {
        const int sub = it >> 2, off = ((it & 3) * 256 + t) * 16;
        const int ro = off >> 7, col = off & 127;
        *(uint4*)((char*)&Kb[(H2 + 1) & 1][0] + sub * 16384 + ro * 128 + (col ^ ((ro & 7) << 4))) = pre[it];
      }
      __syncthreads();
    }
  }
  // Kb dead from here; Ps overlays it — barrier so no wave still reads K
  __syncthreads();
  // write attn_mean (f32) + Ps (bf16)
  #pragma unroll
  for (int rf = 0; rf < 2; ++rf)
    #pragma unroll
    for (int kt = 0; kt < 2; ++kt)
      #pragma unroll
      for (int cf = 0; cf < 4; ++cf)
        #pragma unroll
        for (int reg = 0; reg < 4; ++reg) {
          const int qrow = qw + rf * 16 + lg * 4 + reg;
          const int col = k00 + kt * 64 + cf * 16 + lr;
          const float p = pm[rf][kt][cf][reg];
          attn_out[((size_t)(b * 2048 + qrow) << 11) + col] = p;
          Ps[w * 32 + rf * 16 + lg * 4 + reg][kt * 64 + cf * 16 + lr] = f2bf(p);
        }
  // PV: same-wave rows of Ps, V-frags from L2-resident vpt
  const f32x4 zf = {0.f, 0.f, 0.f, 0.f};
  f32x4 ctx[2][4];
  #pragma unroll
  for (int rf = 0; rf < 2; ++rf)
    #pragma unroll
    for (int dcf = 0; dcf < 4; ++dcf) ctx[rf][dcf] = zf;
  #pragma unroll
  for (int k2 = 0; k2 < 4; ++k2) {
    bf16x8 ap[2];
    #pragma unroll
    for (int rf = 0; rf < 2; ++rf)
      ap[rf] = load8(&Ps[w * 32 + rf * 16 + lr][k2 * 32 + lg * 8]);
    #pragma unroll
    for (int dcf = 0; dcf < 4; ++dcf) {
      const bf16x8 bvf = load8(vpt + ((size_t)(b * 64 + dcf * 16 + lr)) * 2048 + k00 + k2 * 32 + lg * 8);
      #pragma unroll
      for (int rf = 0; rf < 2; ++rf) ctx[rf][dcf] = mfma16(ap[rf], bvf, ctx[rf][dcf]);
    }
  }
  #pragma unroll
  for (int rf = 0; rf < 2; ++rf)
    #pragma unroll
    for (int dcf = 0; dcf < 4; ++dcf)
      #pragma unroll
      for (int reg = 0; reg < 4; ++reg) {
        const int m = b * 2048 + qw + rf * 16 + lg * 4 + reg;
        ctxp[((size_t)(ksb * 4096 + m) << 6) + dcf * 16 + lr] = ctx[rf][dcf][reg];
      }
}

// ---------------- ctx reduce: ctxr[m][d] bf16 = sum_ks ctxp ----------------
__global__ __launch_bounds__(256) void imha_ctxred(
    const float* __restrict__ ctxp, unsigned short* __restrict__ ctxr) {
  const int i4 = (blockIdx.x * 256 + threadIdx.x) * 4;  // 262144 elems
  float4 s = {0.f, 0.f, 0.f, 0.f};
  #pragma unroll
  for (int p = 0; p < 16; ++p) {
    const float4 v = *(const float4*)&ctxp[(size_t)p * 262144 + i4];
    s.x += v.x; s.y += v.y; s.z += v.z; s.w += v.w;
  }
  ushort4 o;
  o.x = f2bf(s.x); o.y = f2bf(s.y); o.z = f2bf(s.z); o.w = f2bf(s.w);
  *(ushort4*)&ctxr[i4] = o;
}

// ---------------- out projection: out = ctxr @ Wo + bo ---------------------
__global__ __launch_bounds__(256) void imha_outproj(
    const unsigned short* __restrict__ ctxr, const unsigned short* __restrict__ wot,
    const float* __restrict__ bo, float* __restrict__ out) {
  __shared__ unsigned short As[128][72];
  __shared__ unsigned short Bs[128][72];
  const int t = threadIdx.x, l = t & 63, w = t >> 6, lr = l & 15, lg = l >> 4;
  const int m0 = blockIdx.x * 128, n0 = blockIdx.y * 128;
  const int wr = w >> 1, wc = w & 1;
  {
    const int r = t >> 1, cs = (t & 1) * 32;
    #pragma unroll
    for (int i = 0; i < 4; ++i)
      *(uint4*)&As[r][cs + i * 8] = *(const uint4*)&ctxr[(m0 + r) * 64 + cs + i * 8];
    #pragma unroll
    for (int i = 0; i < 4; ++i)
      *(uint4*)&Bs[r][cs + i * 8] = *(const uint4*)&wot[(n0 + r) * 64 + cs + i * 8];
  }
  __syncthreads();
  const f32x4 zf = {0.f, 0.f, 0.f, 0.f};
  f32x4 acc[4][4];
  #pragma unroll
  for (int i = 0; i < 4; ++i)
    #pragma unroll
    for (int j = 0; j < 4; ++j) acc[i][j] = zf;
  #pragma unroll
  for (int k2 = 0; k2 < 2; ++k2) {
    bf16x8 a[4], bb[4];
    #pragma unroll
    for (int i = 0; i < 4; ++i) a[i] = load8(&As[wr * 64 + i * 16 + lr][k2 * 32 + lg * 8]);
    #pragma unroll
    for (int i = 0; i < 4; ++i) bb[i] = load8(&Bs[wc * 64 + i * 16 + lr][k2 * 32 + lg * 8]);
    #pragma unroll
    for (int i = 0; i < 4; ++i)
      #pragma unroll
      for (int j = 0; j < 4; ++j) acc[i][j] = mfma16(a[i], bb[j], acc[i][j]);
  }
  #pragma unroll
  for (int j = 0; j < 4; ++j) {
    const int gn = n0 + wc * 64 + j * 16 + lr;
    const float bv = bo[gn];
    #pragma unroll
    for (int i = 0; i < 4; ++i) {
      #pragma unroll
      for (int r = 0; r < 4; ++r) {
        const int gm = m0 + wr * 64 + i * 16 + lg * 4 + r;
        out[((size_t)gm << 10) + gn] = acc[i][j][r] + bv;
      }
    }
  }
}

// ---------------- host launch ----------------------------------------------
extern "C" void kernel_launch(void* const* d_in, const int* in_sizes, int n_in,
                              void* d_out, int out_size, void* d_ws, size_t ws_size,
                              hipStream_t stream) {
  const float* q  = (const float*)d_in[0];
  const float* k  = (const float*)d_in[1];
  const float* v  = (const float*)d_in[2];
  const int*  mask = (const int*)d_in[3];
  const float* Wq = (const float*)d_in[4];
  const float* bq = (const float*)d_in[5];
  const float* Wk = (const float*)d_in[6];
  const float* bk = (const float*)d_in[7];
  const float* Wv = (const float*)d_in[8];
  const float* bv = (const float*)d_in[9];
  const float* Wo = (const float*)d_in[10];
  const float* bo = (const float*)d_in[11];

  char* ws = (char*)d_ws;
  unsigned short* wqt  = (unsigned short*)(ws + 0);          // 2 MB
  unsigned short* wkt  = (unsigned short*)(ws + 2097152);    // 2 MB
  unsigned short* wot  = (unsigned short*)(ws + 4194304);    // 128 KB
  unsigned*       mb   = (unsigned*)      (ws + 4325376);    // 512 KB
  unsigned short* qhb  = (unsigned short*)(ws + 4849664);    // 8 MB
  unsigned short* khb  = (unsigned short*)(ws + 13238272);   // 8 MB
  unsigned short* vpt  = (unsigned short*)(ws + 21626880);   // 512 KB
  float*          linv = (float*)         (ws + 22151168);   // 256 KB
  float*          ctxp = (float*)         (ws + 22413312);   // 16 MB -> ends 39190528
  unsigned short* ctxr = (unsigned short*)(ws + 39190528);   // 512 KB -> ends 39702528
  // aliases inside ctxp region (dead at time of use):
  unsigned short* wvt  = (unsigned short*)(ws + 22413312);             // 128 KB, dead after vproj_mm
  float*          ctxvp= (float*)         (ws + 22413312 + 131072);    // 8 MB, dead after vred
  float*          lpart16 = (float*)      (ws + 22413312);             // 4 MB, dead before pass2

  float* out  = (float*)d_out;
  float* attn = out + (size_t)BB * SS * DD;  // 4,194,304

  const float qScale = 0.125f * 1.44269504088896340736f;  // fold log2(e) for exp2

  imha_prep<<<3072, 256, 0, stream>>>(Wq, Wk, Wo, Wv, mask, wqt, wkt, wot, wvt, mb);
  imha_vproj_mm<<<dim3(64, 8), 256, 0, stream>>>(v, wvt, ctxvp);
  imha_vred<<<32, 256, 0, stream>>>(ctxvp, bv, vpt);
  imha_proj<<<dim3(64, 8), 256, 0, stream>>>(q, wqt, bq, qhb, qScale);
  imha_proj<<<dim3(64, 8), 256, 0, stream>>>(k, wkt, bk, khb, 1.0f);
  imha_pass1<<<512, 256, 0, stream>>>(qhb, khb, mb, lpart16);
  imha_linv<<<256, 256, 0, stream>>>(lpart16, linv);
  imha_pass2<<<512, 256, 0, stream>>>(qhb, khb, vpt, mb, linv, attn, ctxp);
  imha_ctxred<<<256, 256, 0, stream>>>(ctxp, ctxr);
  imha_outproj<<<dim3(32, 8), 256, 0, stream>>>(ctxr, wot, bo, out);
}

// Round 14
// 222.050 us; speedup vs baseline: 1.5984x; 1.5984x over previous
//
#include <hip/hip_runtime.h>
#include <hip/hip_bf16.h>

// Problem constants
#define BB 2
#define SS 2048
#define DD 1024
#define HH 16
#define DP 64

typedef __bf16 bf16x8 __attribute__((ext_vector_type(8)));
typedef float f32x4 __attribute__((ext_vector_type(4)));

__device__ __forceinline__ unsigned short f2bf(float f) {
  unsigned u = __float_as_uint(f);
  unsigned r = u + 0x7FFFu + ((u >> 16) & 1u);
  return (unsigned short)(r >> 16);
}

__device__ __forceinline__ bf16x8 load8(const unsigned short* p) {
  return __builtin_bit_cast(bf16x8, *(const uint4*)p);
}

__device__ __forceinline__ f32x4 mfma16(bf16x8 a, bf16x8 b, f32x4 c) {
  return __builtin_amdgcn_mfma_f32_16x16x32_bf16(a, b, c, 0, 0, 0);
}

// ---------------- prep: transpose+convert weights, pack mask bits ----------
__global__ __launch_bounds__(256) void imha_prep(
    const float* __restrict__ Wq, const float* __restrict__ Wk,
    const float* __restrict__ Wo, const float* __restrict__ Wv,
    const int* __restrict__ mask,
    unsigned short* __restrict__ wqt, unsigned short* __restrict__ wkt,
    unsigned short* __restrict__ wot, unsigned short* __restrict__ wvt,
    unsigned* __restrict__ mb) {
  const int bx = blockIdx.x, t = threadIdx.x;
  if (bx < 2048) {
    const float* src = (bx < 1024) ? Wq : Wk;
    unsigned short* dst = (bx < 1024) ? wqt : wkt;
    const int tile = bx & 1023;
    const int ty = tile >> 5, tx = tile & 31;
    __shared__ float T[32][33];
    const int r = t >> 3, c4 = (t & 7) * 4;
    const float4 v = *(const float4*)&src[(ty * 32 + r) * 1024 + tx * 32 + c4];
    T[r][c4 + 0] = v.x; T[r][c4 + 1] = v.y; T[r][c4 + 2] = v.z; T[r][c4 + 3] = v.w;
    __syncthreads();
    ushort4 o;
    o.x = f2bf(T[c4 + 0][r]); o.y = f2bf(T[c4 + 1][r]);
    o.z = f2bf(T[c4 + 2][r]); o.w = f2bf(T[c4 + 3][r]);
    *(ushort4*)&dst[(tx * 32 + r) * 1024 + ty * 32 + c4] = o;
  } else if (bx < 2304) {
    const int idx = (bx - 2048) * 256 + t;
    const int n = idx >> 6, k = idx & 63;
    wot[idx] = f2bf(Wo[k * 1024 + n]);
  } else if (bx < 2816) {
    const int widx = (bx - 2304) * 256 + t;  // 131072 words
    const int qr = widx >> 6, wd = widx & 63;
    const int* mrow = mask + qr * 2048 + wd * 32;
    unsigned wv = 0;
    #pragma unroll
    for (int j4 = 0; j4 < 8; ++j4) {
      const int4 m4 = *(const int4*)&mrow[j4 * 4];
      wv |= (unsigned)(m4.x & 1) << (j4 * 4);
      wv |= (unsigned)(m4.y & 1) << (j4 * 4 + 1);
      wv |= (unsigned)(m4.z & 1) << (j4 * 4 + 2);
      wv |= (unsigned)(m4.w & 1) << (j4 * 4 + 3);
    }
    mb[widx] = wv;
  } else {
    const int widx = (bx - 2816) * 256 + t;  // 65536
    const int k = widx >> 6, n = widx & 63;
    wvt[n * 1024 + k] = f2bf(Wv[widx]);
  }
}

// ---------------- projection GEMM (BM=64, BN=128) --------------------------
__global__ __launch_bounds__(256) void imha_proj(
    const float* __restrict__ X, const unsigned short* __restrict__ Wt,
    const float* __restrict__ bias, unsigned short* __restrict__ dst,
    float preScale) {
  __shared__ unsigned short As[64][40];
  __shared__ unsigned short Bs[128][40];
  const int t = threadIdx.x, l = t & 63, w = t >> 6, lr = l & 15, lg = l >> 4;
  const int m0 = blockIdx.x * 64, n0 = blockIdx.y * 128;
  const int wr = w >> 1, wc = w & 1;
  const f32x4 zf = {0.f, 0.f, 0.f, 0.f};
  f32x4 acc[2][4];
  #pragma unroll
  for (int i = 0; i < 2; ++i)
    #pragma unroll
    for (int j = 0; j < 4; ++j) acc[i][j] = zf;

  for (int kk = 0; kk < 32; ++kk) {
    {
      const int rA = t >> 2, cA = (t & 3) * 8;
      const float4 v0 = *(const float4*)&X[(m0 + rA) * 1024 + kk * 32 + cA];
      const float4 v1 = *(const float4*)&X[(m0 + rA) * 1024 + kk * 32 + cA + 4];
      ushort4 o0, o1;
      o0.x = f2bf(v0.x); o0.y = f2bf(v0.y); o0.z = f2bf(v0.z); o0.w = f2bf(v0.w);
      o1.x = f2bf(v1.x); o1.y = f2bf(v1.y); o1.z = f2bf(v1.z); o1.w = f2bf(v1.w);
      *(ushort4*)&As[rA][cA] = o0;
      *(ushort4*)&As[rA][cA + 4] = o1;
      const int rB = t >> 2, cB = (t & 3) * 8;
      #pragma unroll
      for (int p = 0; p < 2; ++p) {
        const uint4 u = *(const uint4*)&Wt[(n0 + p * 64 + rB) * 1024 + kk * 32 + cB];
        *(uint4*)&Bs[p * 64 + rB][cB] = u;
      }
    }
    __syncthreads();
    bf16x8 a[2], bf[4];
    #pragma unroll
    for (int i = 0; i < 2; ++i) a[i] = load8(&As[wr * 32 + i * 16 + lr][lg * 8]);
    #pragma unroll
    for (int j = 0; j < 4; ++j) bf[j] = load8(&Bs[wc * 64 + j * 16 + lr][lg * 8]);
    #pragma unroll
    for (int i = 0; i < 2; ++i)
      #pragma unroll
      for (int j = 0; j < 4; ++j) acc[i][j] = mfma16(a[i], bf[j], acc[i][j]);
    __syncthreads();
  }
  #pragma unroll
  for (int j = 0; j < 4; ++j) {
    const int gn = n0 + wc * 64 + j * 16 + lr;
    const float bv = bias[gn];
    const int h = gn >> 6, d = gn & 63;
    #pragma unroll
    for (int i = 0; i < 2; ++i) {
      #pragma unroll
      for (int r = 0; r < 4; ++r) {
        const int gm = m0 + wr * 32 + i * 16 + lg * 4 + r;
        const int b = gm >> 11, s = gm & 2047;
        dst[(((b * 16 + h) * 2048 + s) << 6) + d] = f2bf((acc[i][j][r] + bv) * preScale);
      }
    }
  }
}

// ---------------- V projection (MFMA, K-split): partials -------------------
__global__ __launch_bounds__(256) void imha_vproj_mm(
    const float* __restrict__ V, const unsigned short* __restrict__ wvt,
    float* __restrict__ ctxvp) {
  const int t = threadIdx.x, l = t & 63, w = t >> 6, lr = l & 15, lg = l >> 4;
  const int m0 = blockIdx.x * 64 + w * 16;
  const int k0 = blockIdx.y * 128;
  const f32x4 zf = {0.f, 0.f, 0.f, 0.f};
  f32x4 acc[4];
  #pragma unroll
  for (int j = 0; j < 4; ++j) acc[j] = zf;
  #pragma unroll
  for (int kk = 0; kk < 4; ++kk) {
    const int kb = k0 + kk * 32 + lg * 8;
    const float4 v0 = *(const float4*)&V[(m0 + lr) * 1024 + kb];
    const float4 v1 = *(const float4*)&V[(m0 + lr) * 1024 + kb + 4];
    union { bf16x8 v; unsigned short u[8]; } au;
    au.u[0] = f2bf(v0.x); au.u[1] = f2bf(v0.y); au.u[2] = f2bf(v0.z); au.u[3] = f2bf(v0.w);
    au.u[4] = f2bf(v1.x); au.u[5] = f2bf(v1.y); au.u[6] = f2bf(v1.z); au.u[7] = f2bf(v1.w);
    #pragma unroll
    for (int j = 0; j < 4; ++j) {
      const bf16x8 bfr = load8(&wvt[(j * 16 + lr) * 1024 + kb]);
      acc[j] = mfma16(au.v, bfr, acc[j]);
    }
  }
  #pragma unroll
  for (int j = 0; j < 4; ++j)
    #pragma unroll
    for (int reg = 0; reg < 4; ++reg) {
      const int m = m0 + lg * 4 + reg;
      ctxvp[((size_t)blockIdx.y * 4096 + m) * 64 + j * 16 + lr] = acc[j][reg];
    }
}

// ---------------- reduce partials -> vpT[b,d,s] bf16 -----------------------
__global__ __launch_bounds__(256) void imha_vred(
    const float* __restrict__ ctxvp, const float* __restrict__ bv,
    unsigned short* __restrict__ vpt) {
  __shared__ float T[128][65];
  const int t = threadIdx.x;
  const int m0 = blockIdx.x * 128;  // 32 blocks
  #pragma unroll
  for (int i = 0; i < 32; ++i) {
    const int e = t + i * 256;
    float s = 0.f;
    #pragma unroll
    for (int p = 0; p < 8; ++p) s += ctxvp[(size_t)p * 262144 + (size_t)m0 * 64 + e];
    T[e >> 6][e & 63] = s;
  }
  __syncthreads();
  const int d = t >> 2, sc = (t & 3) * 32;
  const int b = m0 >> 11, srow = m0 & 2047;
  const float bias = bv[d];
  unsigned short* dst = vpt + ((size_t)b * 64 + d) * 2048 + srow + sc;
  #pragma unroll
  for (int i = 0; i < 32; i += 8) {
    ushort4 o0, o1;
    o0.x = f2bf(T[sc + i + 0][d] + bias); o0.y = f2bf(T[sc + i + 1][d] + bias);
    o0.z = f2bf(T[sc + i + 2][d] + bias); o0.w = f2bf(T[sc + i + 3][d] + bias);
    o1.x = f2bf(T[sc + i + 4][d] + bias); o1.y = f2bf(T[sc + i + 5][d] + bias);
    o1.z = f2bf(T[sc + i + 6][d] + bias); o1.w = f2bf(T[sc + i + 7][d] + bias);
    *(ushort4*)(dst + i) = o0;
    *(ushort4*)(dst + i + 4) = o1;
  }
}

// ---------------- pass1 (h-major): per-head exp2 row-partials --------------
// 512 blocks (XCD-swizzled): block = (q-tile 128, b*16+h); streams 16 K-tiles
// of 128 rows through dbuf LDS. Q hoisted. No shfl: 16 lane-partials per row.
__global__ __launch_bounds__(256, 3) void imha_pass1(
    const unsigned short* __restrict__ qhb, const unsigned short* __restrict__ khb,
    const unsigned* __restrict__ mb, float* __restrict__ lpart16) {
  __shared__ unsigned short Kb[2][8192];  // 2 x 128x64 bf16, XOR-swizzled
  const int t = threadIdx.x, l = t & 63, w = t >> 6, lr = l & 15, lg = l >> 4;
  const int orig = blockIdx.x;                       // 512
  const int swz = (orig & 7) * 64 + (orig >> 3);     // XCD-chunked
  const int q0 = (swz & 15) * 128, bh = swz >> 4;
  const int qw = q0 + w * 32;
  // hoisted Q fragments
  const unsigned short* qb = qhb + ((size_t)(bh * 2048 + qw) << 6);
  bf16x8 aq[2][2];
  #pragma unroll
  for (int rf = 0; rf < 2; ++rf)
    #pragma unroll
    for (int k2 = 0; k2 < 2; ++k2)
      aq[rf][k2] = load8(qb + (((rf * 16 + lr) << 6) + k2 * 32 + lg * 8));
  const unsigned short* kbase = khb + ((size_t)bh << 17);  // bh*2048*64
  uint4 pre[4];
  #pragma unroll
  for (int it = 0; it < 4; ++it)
    pre[it] = *(const uint4*)((const char*)kbase + (it * 256 + t) * 16);
  #pragma unroll
  for (int it = 0; it < 4; ++it) {
    const int off = (it * 256 + t) * 16, row = off >> 7, col = off & 127;
    *(uint4*)((char*)&Kb[0][0] + row * 128 + (col ^ ((row & 7) << 4))) = pre[it];
  }
  __syncthreads();
  float lsum[2][4] = {0.f, 0.f, 0.f, 0.f, 0.f, 0.f, 0.f, 0.f};
  #pragma unroll 1
  for (int kt = 0; kt < 16; ++kt) {
    if (kt < 15) {
      const char* nk = (const char*)kbase + (kt + 1) * 16384;
      #pragma unroll
      for (int it = 0; it < 4; ++it)
        pre[it] = *(const uint4*)(nk + (it * 256 + t) * 16);
    }
    // mask words for this k-tile: 128 bits per owned q-row
    uint4 mw[2][4];
    #pragma unroll
    for (int rf = 0; rf < 2; ++rf)
      #pragma unroll
      for (int reg = 0; reg < 4; ++reg) {
        const int qrow = qw + rf * 16 + lg * 4 + reg;
        mw[rf][reg] = *(const uint4*)&mb[qrow * 64 + kt * 4];
      }
    const char* kl = (const char*)&Kb[kt & 1][0];
    const int sxor = (lr & 7) << 4;
    __builtin_amdgcn_s_setprio(1);
    #pragma unroll
    for (int cf = 0; cf < 8; ++cf) {
      const int row = cf * 16 + lr;
      const bf16x8 b0 = load8((const unsigned short*)(kl + row * 128 + ((lg * 16) ^ sxor)));
      const bf16x8 b1 = load8((const unsigned short*)(kl + row * 128 + ((64 + lg * 16) ^ sxor)));
      #pragma unroll
      for (int rf = 0; rf < 2; ++rf) {
        f32x4 aini;
        #pragma unroll
        for (int reg = 0; reg < 4; ++reg) {
          const unsigned word = ((const unsigned*)&mw[rf][reg])[cf >> 1];
          const unsigned bit = (word >> (((cf & 1) << 4) + lr)) & 1u;
          aini[reg] = bit ? -30000.0f : 0.0f;
        }
        f32x4 acc = mfma16(aq[rf][0], b0, aini);
        acc = mfma16(aq[rf][1], b1, acc);
        #pragma unroll
        for (int reg = 0; reg < 4; ++reg)
          lsum[rf][reg] += __builtin_exp2f(acc[reg]);
      }
    }
    __builtin_amdgcn_s_setprio(0);
    if (kt < 15) {
      #pragma unroll
      for (int it = 0; it < 4; ++it) {
        const int off = (it * 256 + t) * 16, row = off >> 7, col = off & 127;
        *(uint4*)((char*)&Kb[(kt + 1) & 1][0] + row * 128 + (col ^ ((row & 7) << 4))) = pre[it];
      }
      __syncthreads();
    }
  }
  // unreduced 16-lane partials: lpart16[(bh*2048+q)*16 + lr]
  #pragma unroll
  for (int rf = 0; rf < 2; ++rf)
    #pragma unroll
    for (int reg = 0; reg < 4; ++reg) {
      const int qrow = bh * 2048 + qw + rf * 16 + lg * 4 + reg;
      lpart16[(qrow << 4) + lr] = lsum[rf][reg];
    }
}

// ---------------- linv = (1/16) / sum(lpart16) -----------------------------
__global__ __launch_bounds__(256) void imha_linv(
    const float* __restrict__ lpart16, float* __restrict__ linv) {
  const int i = blockIdx.x * 256 + threadIdx.x;  // 65536
  const float4* p = (const float4*)&lpart16[i << 4];
  float s = 0.f;
  #pragma unroll
  for (int j = 0; j < 4; ++j) {
    const float4 v = p[j];
    s += v.x + v.y + v.z + v.w;
  }
  linv[i] = 0.0625f / s;
}

// ---------------- pass2: attn_mean + partial ctx (K in LDS, Ps unioned) ----
// 512 blocks (XCD-swizzled): q-tile 128 (4 waves x 32q), k-tile 128, h-loop 16
// launch_bounds(256,2): NO register cap (R10's (256,4) caused massive spill);
// occupancy comes from the 34.8KB LDS union -> 4 blocks/CU at VGPR~92.
__global__ __launch_bounds__(256, 2) void imha_pass2(
    const unsigned short* __restrict__ qhb, const unsigned short* __restrict__ khb,
    const unsigned short* __restrict__ vpt, const unsigned* __restrict__ mb,
    const float* __restrict__ linv, float* __restrict__ attn_out,
    float* __restrict__ ctxp) {
  // union: Kb[2][8192] shorts (32 KB, h-loop) | Ps[128][136] shorts (34 KB, epilogue)
  __shared__ char smem[34816];
  unsigned short (*Kb)[8192] = (unsigned short(*)[8192])smem;
  unsigned short (*Ps)[136] = (unsigned short(*)[136])smem;
  const int t = threadIdx.x, l = t & 63, w = t >> 6, lr = l & 15, lg = l >> 4;
  const int orig = blockIdx.x;                    // 512
  const int swz = (orig & 7) * 64 + (orig >> 3);  // XCD-chunked
  const int q0 = (swz & 15) * 128, ksb = (swz >> 4) & 15, b = swz >> 8;
  const int k00 = ksb * 128;
  const int qw = q0 + w * 32;
  f32x4 aini[2][2][4];
  #pragma unroll
  for (int rf = 0; rf < 2; ++rf)
    #pragma unroll
    for (int reg = 0; reg < 4; ++reg) {
      const int qrow = qw + rf * 16 + lg * 4 + reg;
      const unsigned* mrow = mb + qrow * 64;
      #pragma unroll
      for (int kt = 0; kt < 2; ++kt)
        #pragma unroll
        for (int cf = 0; cf < 4; ++cf) {
          const unsigned word = mrow[(k00 + kt * 64 + cf * 16) >> 5];
          const unsigned bit = (word >> (((cf & 1) << 4) + lr)) & 1u;
          aini[rf][kt][cf][reg] = bit ? -30000.0f : 0.0f;
        }
    }
  float pm[2][2][4][4];
  #pragma unroll
  for (int a = 0; a < 2; ++a)
    #pragma unroll
    for (int c = 0; c < 2; ++c)
      #pragma unroll
      for (int d2 = 0; d2 < 4; ++d2)
        #pragma unroll
        for (int e = 0; e < 4; ++e) pm[a][c][d2][e] = 0.f;

  const unsigned short* kbase = khb + ((size_t)((b * 16) * 2048 + k00) << 6);
  uint4 pre[4];
  #pragma unroll
  for (int it = 0; it < 4; ++it)
    pre[it] = *(const uint4*)((const char*)kbase + (it * 256 + t) * 16);
  #pragma unroll
  for (int it = 0; it < 4; ++it) {
    const int off = (it * 256 + t) * 16, row = off >> 7, col = off & 127;
    *(uint4*)((char*)&Kb[0][0] + row * 128 + (col ^ ((row & 7) << 4))) = pre[it];
  }
  __syncthreads();
  #pragma unroll 1
  for (int h = 0; h < 16; ++h) {
    if (h < 15) {
      const char* nk = (const char*)(kbase + ((size_t)(h + 1) << 17));
      #pragma unroll
      for (int it = 0; it < 4; ++it)
        pre[it] = *(const uint4*)(nk + (it * 256 + t) * 16);
    }
    const unsigned short* qb = qhb + ((size_t)((b * 16 + h) * 2048 + qw) << 6);
    bf16x8 aq[2][2];
    #pragma unroll
    for (int rf = 0; rf < 2; ++rf)
      #pragma unroll
      for (int k2 = 0; k2 < 2; ++k2)
        aq[rf][k2] = load8(qb + (((rf * 16 + lr) << 6) + k2 * 32 + lg * 8));
    float4 li4[2];
    #pragma unroll
    for (int rf = 0; rf < 2; ++rf)
      li4[rf] = *(const float4*)&linv[(b * 16 + h) * 2048 + qw + rf * 16 + lg * 4];
    const char* kl = (const char*)&Kb[h & 1][0];
    const int sxor = (lr & 7) << 4;
    __builtin_amdgcn_s_setprio(1);
    #pragma unroll
    for (int kt = 0; kt < 2; ++kt) {
      #pragma unroll
      for (int cf = 0; cf < 4; ++cf) {
        const int row = kt * 64 + cf * 16 + lr;
        const bf16x8 b0 = load8((const unsigned short*)(kl + row * 128 + ((lg * 16) ^ sxor)));
        const bf16x8 b1 = load8((const unsigned short*)(kl + row * 128 + ((64 + lg * 16) ^ sxor)));
        #pragma unroll
        for (int rf = 0; rf < 2; ++rf) {
          f32x4 acc = mfma16(aq[rf][0], b0, aini[rf][kt][cf]);
          acc = mfma16(aq[rf][1], b1, acc);
          const float* lip = (const float*)&li4[rf];
          #pragma unroll
          for (int reg = 0; reg < 4; ++reg)
            pm[rf][kt][cf][reg] += __builtin_exp2f(acc[reg]) * lip[reg];
        }
      }
    }
    __builtin_amdgcn_s_setprio(0);
    if (h < 15) {
      #pragma unroll
      for (int it = 0; it < 4; ++it) {
        const int off = (it * 256 + t) * 16, row = off >> 7, col = off & 127;
        *(uint4*)((char*)&Kb[(h + 1) & 1][0] + row * 128 + (col ^ ((row & 7) << 4))) = pre[it];
      }
      __syncthreads();
    }
  }
  // Kb dead from here; Ps overlays it — barrier so no wave still reads K
  __syncthreads();
  // write attn_mean (f32) + Ps (bf16)
  #pragma unroll
  for (int rf = 0; rf < 2; ++rf)
    #pragma unroll
    for (int kt = 0; kt < 2; ++kt)
      #pragma unroll
      for (int cf = 0; cf < 4; ++cf)
        #pragma unroll
        for (int reg = 0; reg < 4; ++reg) {
          const int qrow = qw + rf * 16 + lg * 4 + reg;
          const int col = k00 + kt * 64 + cf * 16 + lr;
          const float p = pm[rf][kt][cf][reg];
          attn_out[((size_t)(b * 2048 + qrow) << 11) + col] = p;
          Ps[w * 32 + rf * 16 + lg * 4 + reg][kt * 64 + cf * 16 + lr] = f2bf(p);
        }
  // PV: same-wave rows of Ps, V-frags from L2-resident vpt
  const f32x4 zf = {0.f, 0.f, 0.f, 0.f};
  f32x4 ctx[2][4];
  #pragma unroll
  for (int rf = 0; rf < 2; ++rf)
    #pragma unroll
    for (int dcf = 0; dcf < 4; ++dcf) ctx[rf][dcf] = zf;
  #pragma unroll
  for (int k2 = 0; k2 < 4; ++k2) {
    bf16x8 ap[2];
    #pragma unroll
    for (int rf = 0; rf < 2; ++rf)
      ap[rf] = load8(&Ps[w * 32 + rf * 16 + lr][k2 * 32 + lg * 8]);
    #pragma unroll
    for (int dcf = 0; dcf < 4; ++dcf) {
      const bf16x8 bvf = load8(vpt + ((size_t)(b * 64 + dcf * 16 + lr)) * 2048 + k00 + k2 * 32 + lg * 8);
      #pragma unroll
      for (int rf = 0; rf < 2; ++rf) ctx[rf][dcf] = mfma16(ap[rf], bvf, ctx[rf][dcf]);
    }
  }
  #pragma unroll
  for (int rf = 0; rf < 2; ++rf)
    #pragma unroll
    for (int dcf = 0; dcf < 4; ++dcf)
      #pragma unroll
      for (int reg = 0; reg < 4; ++reg) {
        const int m = b * 2048 + qw + rf * 16 + lg * 4 + reg;
        ctxp[((size_t)(ksb * 4096 + m) << 6) + dcf * 16 + lr] = ctx[rf][dcf][reg];
      }
}

// ---------------- ctx reduce: ctxr[m][d] bf16 = sum_ks ctxp ----------------
__global__ __launch_bounds__(256) void imha_ctxred(
    const float* __restrict__ ctxp, unsigned short* __restrict__ ctxr) {
  const int i4 = (blockIdx.x * 256 + threadIdx.x) * 4;  // 262144 elems
  float4 s = {0.f, 0.f, 0.f, 0.f};
  #pragma unroll
  for (int p = 0; p < 16; ++p) {
    const float4 v = *(const float4*)&ctxp[(size_t)p * 262144 + i4];
    s.x += v.x; s.y += v.y; s.z += v.z; s.w += v.w;
  }
  ushort4 o;
  o.x = f2bf(s.x); o.y = f2bf(s.y); o.z = f2bf(s.z); o.w = f2bf(s.w);
  *(ushort4*)&ctxr[i4] = o;
}

// ---------------- out projection: out = ctxr @ Wo + bo ---------------------
__global__ __launch_bounds__(256) void imha_outproj(
    const unsigned short* __restrict__ ctxr, const unsigned short* __restrict__ wot,
    const float* __restrict__ bo, float* __restrict__ out) {
  __shared__ unsigned short As[128][72];
  __shared__ unsigned short Bs[128][72];
  const int t = threadIdx.x, l = t & 63, w = t >> 6, lr = l & 15, lg = l >> 4;
  const int m0 = blockIdx.x * 128, n0 = blockIdx.y * 128;
  const int wr = w >> 1, wc = w & 1;
  {
    const int r = t >> 1, cs = (t & 1) * 32;
    #pragma unroll
    for (int i = 0; i < 4; ++i)
      *(uint4*)&As[r][cs + i * 8] = *(const uint4*)&ctxr[(m0 + r) * 64 + cs + i * 8];
    #pragma unroll
    for (int i = 0; i < 4; ++i)
      *(uint4*)&Bs[r][cs + i * 8] = *(const uint4*)&wot[(n0 + r) * 64 + cs + i * 8];
  }
  __syncthreads();
  const f32x4 zf = {0.f, 0.f, 0.f, 0.f};
  f32x4 acc[4][4];
  #pragma unroll
  for (int i = 0; i < 4; ++i)
    #pragma unroll
    for (int j = 0; j < 4; ++j) acc[i][j] = zf;
  #pragma unroll
  for (int k2 = 0; k2 < 2; ++k2) {
    bf16x8 a[4], bb[4];
    #pragma unroll
    for (int i = 0; i < 4; ++i) a[i] = load8(&As[wr * 64 + i * 16 + lr][k2 * 32 + lg * 8]);
    #pragma unroll
    for (int i = 0; i < 4; ++i) bb[i] = load8(&Bs[wc * 64 + i * 16 + lr][k2 * 32 + lg * 8]);
    #pragma unroll
    for (int i = 0; i < 4; ++i)
      #pragma unroll
      for (int j = 0; j < 4; ++j) acc[i][j] = mfma16(a[i], bb[j], acc[i][j]);
  }
  #pragma unroll
  for (int j = 0; j < 4; ++j) {
    const int gn = n0 + wc * 64 + j * 16 + lr;
    const float bv = bo[gn];
    #pragma unroll
    for (int i = 0; i < 4; ++i) {
      #pragma unroll
      for (int r = 0; r < 4; ++r) {
        const int gm = m0 + wr * 64 + i * 16 + lg * 4 + r;
        out[((size_t)gm << 10) + gn] = acc[i][j][r] + bv;
      }
    }
  }
}

// ---------------- host launch ----------------------------------------------
extern "C" void kernel_launch(void* const* d_in, const int* in_sizes, int n_in,
                              void* d_out, int out_size, void* d_ws, size_t ws_size,
                              hipStream_t stream) {
  const float* q  = (const float*)d_in[0];
  const float* k  = (const float*)d_in[1];
  const float* v  = (const float*)d_in[2];
  const int*  mask = (const int*)d_in[3];
  const float* Wq = (const float*)d_in[4];
  const float* bq = (const float*)d_in[5];
  const float* Wk = (const float*)d_in[6];
  const float* bk = (const float*)d_in[7];
  const float* Wv = (const float*)d_in[8];
  const float* bv = (const float*)d_in[9];
  const float* Wo = (const float*)d_in[10];
  const float* bo = (const float*)d_in[11];

  char* ws = (char*)d_ws;
  unsigned short* wqt  = (unsigned short*)(ws + 0);          // 2 MB
  unsigned short* wkt  = (unsigned short*)(ws + 2097152);    // 2 MB
  unsigned short* wot  = (unsigned short*)(ws + 4194304);    // 128 KB
  unsigned*       mb   = (unsigned*)      (ws + 4325376);    // 512 KB
  unsigned short* qhb  = (unsigned short*)(ws + 4849664);    // 8 MB
  unsigned short* khb  = (unsigned short*)(ws + 13238272);   // 8 MB
  unsigned short* vpt  = (unsigned short*)(ws + 21626880);   // 512 KB
  float*          linv = (float*)         (ws + 22151168);   // 256 KB
  float*          ctxp = (float*)         (ws + 22413312);   // 16 MB -> ends 39190528
  unsigned short* ctxr = (unsigned short*)(ws + 39190528);   // 512 KB -> ends 39702528
  // aliases inside ctxp region (dead at time of use):
  unsigned short* wvt  = (unsigned short*)(ws + 22413312);             // 128 KB, dead after vproj_mm
  float*          ctxvp= (float*)         (ws + 22413312 + 131072);    // 8 MB, dead after vred
  float*          lpart16 = (float*)      (ws + 22413312);             // 4 MB, dead before pass2

  float* out  = (float*)d_out;
  float* attn = out + (size_t)BB * SS * DD;  // 4,194,304

  const float qScale = 0.125f * 1.44269504088896340736f;  // fold log2(e) for exp2

  imha_prep<<<3072, 256, 0, stream>>>(Wq, Wk, Wo, Wv, mask, wqt, wkt, wot, wvt, mb);
  imha_vproj_mm<<<dim3(64, 8), 256, 0, stream>>>(v, wvt, ctxvp);
  imha_vred<<<32, 256, 0, stream>>>(ctxvp, bv, vpt);
  imha_proj<<<dim3(64, 8), 256, 0, stream>>>(q, wqt, bq, qhb, qScale);
  imha_proj<<<dim3(64, 8), 256, 0, stream>>>(k, wkt, bk, khb, 1.0f);
  imha_pass1<<<512, 256, 0, stream>>>(qhb, khb, mb, lpart16);
  imha_linv<<<256, 256, 0, stream>>>(lpart16, linv);
  imha_pass2<<<512, 256, 0, stream>>>(qhb, khb, vpt, mb, linv, attn, ctxp);
  imha_ctxred<<<256, 256, 0, stream>>>(ctxp, ctxr);
  imha_outproj<<<dim3(32, 8), 256, 0, stream>>>(ctxr, wot, bo, out);
}

// Round 15
// 207.074 us; speedup vs baseline: 1.7140x; 1.0723x over previous
//
#include <hip/hip_runtime.h>
#include <hip/hip_bf16.h>

// Problem constants
#define BB 2
#define SS 2048
#define DD 1024
#define HH 16
#define DP 64

typedef __bf16 bf16x8 __attribute__((ext_vector_type(8)));
typedef float f32x4 __attribute__((ext_vector_type(4)));

__device__ __forceinline__ unsigned short f2bf(float f) {
  unsigned u = __float_as_uint(f);
  unsigned r = u + 0x7FFFu + ((u >> 16) & 1u);
  return (unsigned short)(r >> 16);
}

__device__ __forceinline__ bf16x8 load8(const unsigned short* p) {
  return __builtin_bit_cast(bf16x8, *(const uint4*)p);
}

__device__ __forceinline__ f32x4 mfma16(bf16x8 a, bf16x8 b, f32x4 c) {
  return __builtin_amdgcn_mfma_f32_16x16x32_bf16(a, b, c, 0, 0, 0);
}

// ---------------- prep: transpose+convert weights, pack mask bits ----------
__global__ __launch_bounds__(256) void imha_prep(
    const float* __restrict__ Wq, const float* __restrict__ Wk,
    const float* __restrict__ Wo, const float* __restrict__ Wv,
    const int* __restrict__ mask,
    unsigned short* __restrict__ wqt, unsigned short* __restrict__ wkt,
    unsigned short* __restrict__ wot, unsigned short* __restrict__ wvt,
    unsigned* __restrict__ mb) {
  const int bx = blockIdx.x, t = threadIdx.x;
  if (bx < 2048) {
    const float* src = (bx < 1024) ? Wq : Wk;
    unsigned short* dst = (bx < 1024) ? wqt : wkt;
    const int tile = bx & 1023;
    const int ty = tile >> 5, tx = tile & 31;
    __shared__ float T[32][33];
    const int r = t >> 3, c4 = (t & 7) * 4;
    const float4 v = *(const float4*)&src[(ty * 32 + r) * 1024 + tx * 32 + c4];
    T[r][c4 + 0] = v.x; T[r][c4 + 1] = v.y; T[r][c4 + 2] = v.z; T[r][c4 + 3] = v.w;
    __syncthreads();
    ushort4 o;
    o.x = f2bf(T[c4 + 0][r]); o.y = f2bf(T[c4 + 1][r]);
    o.z = f2bf(T[c4 + 2][r]); o.w = f2bf(T[c4 + 3][r]);
    *(ushort4*)&dst[(tx * 32 + r) * 1024 + ty * 32 + c4] = o;
  } else if (bx < 2304) {
    const int idx = (bx - 2048) * 256 + t;
    const int n = idx >> 6, k = idx & 63;
    wot[idx] = f2bf(Wo[k * 1024 + n]);
  } else if (bx < 2816) {
    const int widx = (bx - 2304) * 256 + t;  // 131072 words
    const int qr = widx >> 6, wd = widx & 63;
    const int* mrow = mask + qr * 2048 + wd * 32;
    unsigned wv = 0;
    #pragma unroll
    for (int j4 = 0; j4 < 8; ++j4) {
      const int4 m4 = *(const int4*)&mrow[j4 * 4];
      wv |= (unsigned)(m4.x & 1) << (j4 * 4);
      wv |= (unsigned)(m4.y & 1) << (j4 * 4 + 1);
      wv |= (unsigned)(m4.z & 1) << (j4 * 4 + 2);
      wv |= (unsigned)(m4.w & 1) << (j4 * 4 + 3);
    }
    mb[widx] = wv;
  } else {
    const int widx = (bx - 2816) * 256 + t;  // 65536
    const int k = widx >> 6, n = widx & 63;
    wvt[n * 1024 + k] = f2bf(Wv[widx]);
  }
}

// ---------------- merged Q/K projection GEMM (BM=64, BN=128, BK=64) --------
// grid (64, 8, 2): z=0 -> Q (preScale=qScale), z=1 -> K (preScale=1).
// 1024 independent blocks co-resident: staging of one GEMM overlaps the
// other's MFMA. BK=64 halves barrier count vs BK=32.
__global__ __launch_bounds__(256) void imha_proj2(
    const float* __restrict__ Xq, const float* __restrict__ Xk,
    const unsigned short* __restrict__ Wtq, const unsigned short* __restrict__ Wtk,
    const float* __restrict__ biasq, const float* __restrict__ biask,
    unsigned short* __restrict__ dstq, unsigned short* __restrict__ dstk,
    float qScale) {
  __shared__ unsigned short As[64][72];
  __shared__ unsigned short Bs[128][72];
  const int t = threadIdx.x, l = t & 63, w = t >> 6, lr = l & 15, lg = l >> 4;
  const int m0 = blockIdx.x * 64, n0 = blockIdx.y * 128;
  const bool isQ = (blockIdx.z == 0);
  const float* X = isQ ? Xq : Xk;
  const unsigned short* Wt = isQ ? Wtq : Wtk;
  const float* bias = isQ ? biasq : biask;
  unsigned short* dst = isQ ? dstq : dstk;
  const float preScale = isQ ? qScale : 1.0f;
  const int wr = w >> 1, wc = w & 1;
  const f32x4 zf = {0.f, 0.f, 0.f, 0.f};
  f32x4 acc[2][4];
  #pragma unroll
  for (int i = 0; i < 2; ++i)
    #pragma unroll
    for (int j = 0; j < 4; ++j) acc[i][j] = zf;

  for (int kk = 0; kk < 16; ++kk) {
    {
      // A: 64 rows x 64 cols f32 -> bf16; thread covers 16 consecutive cols
      const int rA = t >> 2, cA = (t & 3) * 16;
      const float* xs = &X[(m0 + rA) * 1024 + kk * 64 + cA];
      const float4 v0 = *(const float4*)(xs + 0);
      const float4 v1 = *(const float4*)(xs + 4);
      const float4 v2 = *(const float4*)(xs + 8);
      const float4 v3 = *(const float4*)(xs + 12);
      union { ushort4 h[2]; uint4 u; } p0, p1;
      p0.h[0].x = f2bf(v0.x); p0.h[0].y = f2bf(v0.y); p0.h[0].z = f2bf(v0.z); p0.h[0].w = f2bf(v0.w);
      p0.h[1].x = f2bf(v1.x); p0.h[1].y = f2bf(v1.y); p0.h[1].z = f2bf(v1.z); p0.h[1].w = f2bf(v1.w);
      p1.h[0].x = f2bf(v2.x); p1.h[0].y = f2bf(v2.y); p1.h[0].z = f2bf(v2.z); p1.h[0].w = f2bf(v2.w);
      p1.h[1].x = f2bf(v3.x); p1.h[1].y = f2bf(v3.y); p1.h[1].z = f2bf(v3.z); p1.h[1].w = f2bf(v3.w);
      *(uint4*)&As[rA][cA] = p0.u;
      *(uint4*)&As[rA][cA + 8] = p1.u;
      // B: 128 rows x 64 cols bf16; thread covers 32 consecutive cols
      const int rB = t >> 1, cB = (t & 1) * 32;
      #pragma unroll
      for (int j = 0; j < 4; ++j)
        *(uint4*)&Bs[rB][cB + j * 8] =
            *(const uint4*)&Wt[(n0 + rB) * 1024 + kk * 64 + cB + j * 8];
    }
    __syncthreads();
    bf16x8 a[2][2], bf[4][2];
    #pragma unroll
    for (int i = 0; i < 2; ++i)
      #pragma unroll
      for (int k2 = 0; k2 < 2; ++k2)
        a[i][k2] = load8(&As[wr * 32 + i * 16 + lr][k2 * 32 + lg * 8]);
    #pragma unroll
    for (int j = 0; j < 4; ++j)
      #pragma unroll
      for (int k2 = 0; k2 < 2; ++k2)
        bf[j][k2] = load8(&Bs[wc * 64 + j * 16 + lr][k2 * 32 + lg * 8]);
    #pragma unroll
    for (int k2 = 0; k2 < 2; ++k2)
      #pragma unroll
      for (int i = 0; i < 2; ++i)
        #pragma unroll
        for (int j = 0; j < 4; ++j)
          acc[i][j] = mfma16(a[i][k2], bf[j][k2], acc[i][j]);
    __syncthreads();
  }
  #pragma unroll
  for (int j = 0; j < 4; ++j) {
    const int gn = n0 + wc * 64 + j * 16 + lr;
    const float bv = bias[gn];
    const int h = gn >> 6, d = gn & 63;
    #pragma unroll
    for (int i = 0; i < 2; ++i) {
      #pragma unroll
      for (int r = 0; r < 4; ++r) {
        const int gm = m0 + wr * 32 + i * 16 + lg * 4 + r;
        const int b = gm >> 11, s = gm & 2047;
        dst[(((b * 16 + h) * 2048 + s) << 6) + d] = f2bf((acc[i][j][r] + bv) * preScale);
      }
    }
  }
}

// ---------------- V projection (MFMA, K-split): partials -------------------
__global__ __launch_bounds__(256) void imha_vproj_mm(
    const float* __restrict__ V, const unsigned short* __restrict__ wvt,
    float* __restrict__ ctxvp) {
  const int t = threadIdx.x, l = t & 63, w = t >> 6, lr = l & 15, lg = l >> 4;
  const int m0 = blockIdx.x * 64 + w * 16;
  const int k0 = blockIdx.y * 128;
  const f32x4 zf = {0.f, 0.f, 0.f, 0.f};
  f32x4 acc[4];
  #pragma unroll
  for (int j = 0; j < 4; ++j) acc[j] = zf;
  #pragma unroll
  for (int kk = 0; kk < 4; ++kk) {
    const int kb = k0 + kk * 32 + lg * 8;
    const float4 v0 = *(const float4*)&V[(m0 + lr) * 1024 + kb];
    const float4 v1 = *(const float4*)&V[(m0 + lr) * 1024 + kb + 4];
    union { bf16x8 v; unsigned short u[8]; } au;
    au.u[0] = f2bf(v0.x); au.u[1] = f2bf(v0.y); au.u[2] = f2bf(v0.z); au.u[3] = f2bf(v0.w);
    au.u[4] = f2bf(v1.x); au.u[5] = f2bf(v1.y); au.u[6] = f2bf(v1.z); au.u[7] = f2bf(v1.w);
    #pragma unroll
    for (int j = 0; j < 4; ++j) {
      const bf16x8 bfr = load8(&wvt[(j * 16 + lr) * 1024 + kb]);
      acc[j] = mfma16(au.v, bfr, acc[j]);
    }
  }
  #pragma unroll
  for (int j = 0; j < 4; ++j)
    #pragma unroll
    for (int reg = 0; reg < 4; ++reg) {
      const int m = m0 + lg * 4 + reg;
      ctxvp[((size_t)blockIdx.y * 4096 + m) * 64 + j * 16 + lr] = acc[j][reg];
    }
}

// ---------------- reduce partials -> vpT[b,d,s] bf16 -----------------------
__global__ __launch_bounds__(256) void imha_vred(
    const float* __restrict__ ctxvp, const float* __restrict__ bv,
    unsigned short* __restrict__ vpt) {
  __shared__ float T[128][65];
  const int t = threadIdx.x;
  const int m0 = blockIdx.x * 128;  // 32 blocks
  #pragma unroll
  for (int i = 0; i < 32; ++i) {
    const int e = t + i * 256;
    float s = 0.f;
    #pragma unroll
    for (int p = 0; p < 8; ++p) s += ctxvp[(size_t)p * 262144 + (size_t)m0 * 64 + e];
    T[e >> 6][e & 63] = s;
  }
  __syncthreads();
  const int d = t >> 2, sc = (t & 3) * 32;
  const int b = m0 >> 11, srow = m0 & 2047;
  const float bias = bv[d];
  unsigned short* dst = vpt + ((size_t)b * 64 + d) * 2048 + srow + sc;
  #pragma unroll
  for (int i = 0; i < 32; i += 8) {
    ushort4 o0, o1;
    o0.x = f2bf(T[sc + i + 0][d] + bias); o0.y = f2bf(T[sc + i + 1][d] + bias);
    o0.z = f2bf(T[sc + i + 2][d] + bias); o0.w = f2bf(T[sc + i + 3][d] + bias);
    o1.x = f2bf(T[sc + i + 4][d] + bias); o1.y = f2bf(T[sc + i + 5][d] + bias);
    o1.z = f2bf(T[sc + i + 6][d] + bias); o1.w = f2bf(T[sc + i + 7][d] + bias);
    *(ushort4*)(dst + i) = o0;
    *(ushort4*)(dst + i + 4) = o1;
  }
}

// ---------------- pass1 (h-major): per-head exp2 row-partials --------------
// 512 blocks (XCD-swizzled): block = (q-tile 128, b*16+h); streams 16 K-tiles
// of 128 rows through dbuf LDS. Q hoisted. No shfl: 16 lane-partials per row.
__global__ __launch_bounds__(256, 3) void imha_pass1(
    const unsigned short* __restrict__ qhb, const unsigned short* __restrict__ khb,
    const unsigned* __restrict__ mb, float* __restrict__ lpart16) {
  __shared__ unsigned short Kb[2][8192];  // 2 x 128x64 bf16, XOR-swizzled
  const int t = threadIdx.x, l = t & 63, w = t >> 6, lr = l & 15, lg = l >> 4;
  const int orig = blockIdx.x;                       // 512
  const int swz = (orig & 7) * 64 + (orig >> 3);     // XCD-chunked
  const int q0 = (swz & 15) * 128, bh = swz >> 4;
  const int qw = q0 + w * 32;
  // hoisted Q fragments
  const unsigned short* qb = qhb + ((size_t)(bh * 2048 + qw) << 6);
  bf16x8 aq[2][2];
  #pragma unroll
  for (int rf = 0; rf < 2; ++rf)
    #pragma unroll
    for (int k2 = 0; k2 < 2; ++k2)
      aq[rf][k2] = load8(qb + (((rf * 16 + lr) << 6) + k2 * 32 + lg * 8));
  const unsigned short* kbase = khb + ((size_t)bh << 17);  // bh*2048*64
  uint4 pre[4];
  #pragma unroll
  for (int it = 0; it < 4; ++it)
    pre[it] = *(const uint4*)((const char*)kbase + (it * 256 + t) * 16);
  #pragma unroll
  for (int it = 0; it < 4; ++it) {
    const int off = (it * 256 + t) * 16, row = off >> 7, col = off & 127;
    *(uint4*)((char*)&Kb[0][0] + row * 128 + (col ^ ((row & 7) << 4))) = pre[it];
  }
  __syncthreads();
  float lsum[2][4] = {0.f, 0.f, 0.f, 0.f, 0.f, 0.f, 0.f, 0.f};
  #pragma unroll 1
  for (int kt = 0; kt < 16; ++kt) {
    if (kt < 15) {
      const char* nk = (const char*)kbase + (kt + 1) * 16384;
      #pragma unroll
      for (int it = 0; it < 4; ++it)
        pre[it] = *(const uint4*)(nk + (it * 256 + t) * 16);
    }
    // mask words for this k-tile: 128 bits per owned q-row
    uint4 mw[2][4];
    #pragma unroll
    for (int rf = 0; rf < 2; ++rf)
      #pragma unroll
      for (int reg = 0; reg < 4; ++reg) {
        const int qrow = qw + rf * 16 + lg * 4 + reg;
        mw[rf][reg] = *(const uint4*)&mb[qrow * 64 + kt * 4];
      }
    const char* kl = (const char*)&Kb[kt & 1][0];
    const int sxor = (lr & 7) << 4;
    __builtin_amdgcn_s_setprio(1);
    #pragma unroll
    for (int cf = 0; cf < 8; ++cf) {
      const int row = cf * 16 + lr;
      const bf16x8 b0 = load8((const unsigned short*)(kl + row * 128 + ((lg * 16) ^ sxor)));
      const bf16x8 b1 = load8((const unsigned short*)(kl + row * 128 + ((64 + lg * 16) ^ sxor)));
      #pragma unroll
      for (int rf = 0; rf < 2; ++rf) {
        f32x4 aini;
        #pragma unroll
        for (int reg = 0; reg < 4; ++reg) {
          const unsigned word = ((const unsigned*)&mw[rf][reg])[cf >> 1];
          const unsigned bit = (word >> (((cf & 1) << 4) + lr)) & 1u;
          aini[reg] = bit ? -30000.0f : 0.0f;
        }
        f32x4 acc = mfma16(aq[rf][0], b0, aini);
        acc = mfma16(aq[rf][1], b1, acc);
        #pragma unroll
        for (int reg = 0; reg < 4; ++reg)
          lsum[rf][reg] += __builtin_exp2f(acc[reg]);
      }
    }
    __builtin_amdgcn_s_setprio(0);
    if (kt < 15) {
      #pragma unroll
      for (int it = 0; it < 4; ++it) {
        const int off = (it * 256 + t) * 16, row = off >> 7, col = off & 127;
        *(uint4*)((char*)&Kb[(kt + 1) & 1][0] + row * 128 + (col ^ ((row & 7) << 4))) = pre[it];
      }
      __syncthreads();
    }
  }
  // unreduced 16-lane partials: lpart16[(bh*2048+q)*16 + lr]
  #pragma unroll
  for (int rf = 0; rf < 2; ++rf)
    #pragma unroll
    for (int reg = 0; reg < 4; ++reg) {
      const int qrow = bh * 2048 + qw + rf * 16 + lg * 4 + reg;
      lpart16[(qrow << 4) + lr] = lsum[rf][reg];
    }
}

// ---------------- linv = (1/16) / sum(lpart16) -----------------------------
__global__ __launch_bounds__(256) void imha_linv(
    const float* __restrict__ lpart16, float* __restrict__ linv) {
  const int i = blockIdx.x * 256 + threadIdx.x;  // 65536
  const float4* p = (const float4*)&lpart16[i << 4];
  float s = 0.f;
  #pragma unroll
  for (int j = 0; j < 4; ++j) {
    const float4 v = p[j];
    s += v.x + v.y + v.z + v.w;
  }
  linv[i] = 0.0625f / s;
}

// ---------------- pass2: attn_mean + partial ctx (K in LDS, Ps unioned) ----
// 512 blocks (XCD-swizzled): q-tile 128 (4 waves x 32q), k-tile 128, h-loop 16
// launch_bounds(256,2): NO register cap (R10's (256,4) caused massive spill);
// occupancy comes from the 34.8KB LDS union -> 4 blocks/CU at VGPR~92.
__global__ __launch_bounds__(256, 2) void imha_pass2(
    const unsigned short* __restrict__ qhb, const unsigned short* __restrict__ khb,
    const unsigned short* __restrict__ vpt, const unsigned* __restrict__ mb,
    const float* __restrict__ linv, float* __restrict__ attn_out,
    float* __restrict__ ctxp) {
  // union: Kb[2][8192] shorts (32 KB, h-loop) | Ps[128][136] shorts (34 KB, epilogue)
  __shared__ char smem[34816];
  unsigned short (*Kb)[8192] = (unsigned short(*)[8192])smem;
  unsigned short (*Ps)[136] = (unsigned short(*)[136])smem;
  const int t = threadIdx.x, l = t & 63, w = t >> 6, lr = l & 15, lg = l >> 4;
  const int orig = blockIdx.x;                    // 512
  const int swz = (orig & 7) * 64 + (orig >> 3);  // XCD-chunked
  const int q0 = (swz & 15) * 128, ksb = (swz >> 4) & 15, b = swz >> 8;
  const int k00 = ksb * 128;
  const int qw = q0 + w * 32;
  f32x4 aini[2][2][4];
  #pragma unroll
  for (int rf = 0; rf < 2; ++rf)
    #pragma unroll
    for (int reg = 0; reg < 4; ++reg) {
      const int qrow = qw + rf * 16 + lg * 4 + reg;
      const unsigned* mrow = mb + qrow * 64;
      #pragma unroll
      for (int kt = 0; kt < 2; ++kt)
        #pragma unroll
        for (int cf = 0; cf < 4; ++cf) {
          const unsigned word = mrow[(k00 + kt * 64 + cf * 16) >> 5];
          const unsigned bit = (word >> (((cf & 1) << 4) + lr)) & 1u;
          aini[rf][kt][cf][reg] = bit ? -30000.0f : 0.0f;
        }
    }
  float pm[2][2][4][4];
  #pragma unroll
  for (int a = 0; a < 2; ++a)
    #pragma unroll
    for (int c = 0; c < 2; ++c)
      #pragma unroll
      for (int d2 = 0; d2 < 4; ++d2)
        #pragma unroll
        for (int e = 0; e < 4; ++e) pm[a][c][d2][e] = 0.f;

  const unsigned short* kbase = khb + ((size_t)((b * 16) * 2048 + k00) << 6);
  uint4 pre[4];
  #pragma unroll
  for (int it = 0; it < 4; ++it)
    pre[it] = *(const uint4*)((const char*)kbase + (it * 256 + t) * 16);
  #pragma unroll
  for (int it = 0; it < 4; ++it) {
    const int off = (it * 256 + t) * 16, row = off >> 7, col = off & 127;
    *(uint4*)((char*)&Kb[0][0] + row * 128 + (col ^ ((row & 7) << 4))) = pre[it];
  }
  __syncthreads();
  #pragma unroll 1
  for (int h = 0; h < 16; ++h) {
    if (h < 15) {
      const char* nk = (const char*)(kbase + ((size_t)(h + 1) << 17));
      #pragma unroll
      for (int it = 0; it < 4; ++it)
        pre[it] = *(const uint4*)(nk + (it * 256 + t) * 16);
    }
    const unsigned short* qb = qhb + ((size_t)((b * 16 + h) * 2048 + qw) << 6);
    bf16x8 aq[2][2];
    #pragma unroll
    for (int rf = 0; rf < 2; ++rf)
      #pragma unroll
      for (int k2 = 0; k2 < 2; ++k2)
        aq[rf][k2] = load8(qb + (((rf * 16 + lr) << 6) + k2 * 32 + lg * 8));
    float4 li4[2];
    #pragma unroll
    for (int rf = 0; rf < 2; ++rf)
      li4[rf] = *(const float4*)&linv[(b * 16 + h) * 2048 + qw + rf * 16 + lg * 4];
    const char* kl = (const char*)&Kb[h & 1][0];
    const int sxor = (lr & 7) << 4;
    __builtin_amdgcn_s_setprio(1);
    #pragma unroll
    for (int kt = 0; kt < 2; ++kt) {
      #pragma unroll
      for (int cf = 0; cf < 4; ++cf) {
        const int row = kt * 64 + cf * 16 + lr;
        const bf16x8 b0 = load8((const unsigned short*)(kl + row * 128 + ((lg * 16) ^ sxor)));
        const bf16x8 b1 = load8((const unsigned short*)(kl + row * 128 + ((64 + lg * 16) ^ sxor)));
        #pragma unroll
        for (int rf = 0; rf < 2; ++rf) {
          f32x4 acc = mfma16(aq[rf][0], b0, aini[rf][kt][cf]);
          acc = mfma16(aq[rf][1], b1, acc);
          const float* lip = (const float*)&li4[rf];
          #pragma unroll
          for (int reg = 0; reg < 4; ++reg)
            pm[rf][kt][cf][reg] += __builtin_exp2f(acc[reg]) * lip[reg];
        }
      }
    }
    __builtin_amdgcn_s_setprio(0);
    if (h < 15) {
      #pragma unroll
      for (int it = 0; it < 4; ++it) {
        const int off = (it * 256 + t) * 16, row = off >> 7, col = off & 127;
        *(uint4*)((char*)&Kb[(h + 1) & 1][0] + row * 128 + (col ^ ((row & 7) << 4))) = pre[it];
      }
      __syncthreads();
    }
  }
  // Kb dead from here; Ps overlays it — barrier so no wave still reads K
  __syncthreads();
  // write attn_mean (f32) + Ps (bf16)
  #pragma unroll
  for (int rf = 0; rf < 2; ++rf)
    #pragma unroll
    for (int kt = 0; kt < 2; ++kt)
      #pragma unroll
      for (int cf = 0; cf < 4; ++cf)
        #pragma unroll
        for (int reg = 0; reg < 4; ++reg) {
          const int qrow = qw + rf * 16 + lg * 4 + reg;
          const int col = k00 + kt * 64 + cf * 16 + lr;
          const float p = pm[rf][kt][cf][reg];
          attn_out[((size_t)(b * 2048 + qrow) << 11) + col] = p;
          Ps[w * 32 + rf * 16 + lg * 4 + reg][kt * 64 + cf * 16 + lr] = f2bf(p);
        }
  // PV: same-wave rows of Ps, V-frags from L2-resident vpt
  const f32x4 zf = {0.f, 0.f, 0.f, 0.f};
  f32x4 ctx[2][4];
  #pragma unroll
  for (int rf = 0; rf < 2; ++rf)
    #pragma unroll
    for (int dcf = 0; dcf < 4; ++dcf) ctx[rf][dcf] = zf;
  #pragma unroll
  for (int k2 = 0; k2 < 4; ++k2) {
    bf16x8 ap[2];
    #pragma unroll
    for (int rf = 0; rf < 2; ++rf)
      ap[rf] = load8(&Ps[w * 32 + rf * 16 + lr][k2 * 32 + lg * 8]);
    #pragma unroll
    for (int dcf = 0; dcf < 4; ++dcf) {
      const bf16x8 bvf = load8(vpt + ((size_t)(b * 64 + dcf * 16 + lr)) * 2048 + k00 + k2 * 32 + lg * 8);
      #pragma unroll
      for (int rf = 0; rf < 2; ++rf) ctx[rf][dcf] = mfma16(ap[rf], bvf, ctx[rf][dcf]);
    }
  }
  #pragma unroll
  for (int rf = 0; rf < 2; ++rf)
    #pragma unroll
    for (int dcf = 0; dcf < 4; ++dcf)
      #pragma unroll
      for (int reg = 0; reg < 4; ++reg) {
        const int m = b * 2048 + qw + rf * 16 + lg * 4 + reg;
        ctxp[((size_t)(ksb * 4096 + m) << 6) + dcf * 16 + lr] = ctx[rf][dcf][reg];
      }
}

// ---------------- ctx reduce: ctxr[m][d] bf16 = sum_ks ctxp ----------------
__global__ __launch_bounds__(256) void imha_ctxred(
    const float* __restrict__ ctxp, unsigned short* __restrict__ ctxr) {
  const int i4 = (blockIdx.x * 256 + threadIdx.x) * 4;  // 262144 elems
  float4 s = {0.f, 0.f, 0.f, 0.f};
  #pragma unroll
  for (int p = 0; p < 16; ++p) {
    const float4 v = *(const float4*)&ctxp[(size_t)p * 262144 + i4];
    s.x += v.x; s.y += v.y; s.z += v.z; s.w += v.w;
  }
  ushort4 o;
  o.x = f2bf(s.x); o.y = f2bf(s.y); o.z = f2bf(s.z); o.w = f2bf(s.w);
  *(ushort4*)&ctxr[i4] = o;
}

// ---------------- out projection: out = ctxr @ Wo + bo ---------------------
__global__ __launch_bounds__(256) void imha_outproj(
    const unsigned short* __restrict__ ctxr, const unsigned short* __restrict__ wot,
    const float* __restrict__ bo, float* __restrict__ out) {
  __shared__ unsigned short As[128][72];
  __shared__ unsigned short Bs[128][72];
  const int t = threadIdx.x, l = t & 63, w = t >> 6, lr = l & 15, lg = l >> 4;
  const int m0 = blockIdx.x * 128, n0 = blockIdx.y * 128;
  const int wr = w >> 1, wc = w & 1;
  {
    const int r = t >> 1, cs = (t & 1) * 32;
    #pragma unroll
    for (int i = 0; i < 4; ++i)
      *(uint4*)&As[r][cs + i * 8] = *(const uint4*)&ctxr[(m0 + r) * 64 + cs + i * 8];
    #pragma unroll
    for (int i = 0; i < 4; ++i)
      *(uint4*)&Bs[r][cs + i * 8] = *(const uint4*)&wot[(n0 + r) * 64 + cs + i * 8];
  }
  __syncthreads();
  const f32x4 zf = {0.f, 0.f, 0.f, 0.f};
  f32x4 acc[4][4];
  #pragma unroll
  for (int i = 0; i < 4; ++i)
    #pragma unroll
    for (int j = 0; j < 4; ++j) acc[i][j] = zf;
  #pragma unroll
  for (int k2 = 0; k2 < 2; ++k2) {
    bf16x8 a[4], bb[4];
    #pragma unroll
    for (int i = 0; i < 4; ++i) a[i] = load8(&As[wr * 64 + i * 16 + lr][k2 * 32 + lg * 8]);
    #pragma unroll
    for (int i = 0; i < 4; ++i) bb[i] = load8(&Bs[wc * 64 + i * 16 + lr][k2 * 32 + lg * 8]);
    #pragma unroll
    for (int i = 0; i < 4; ++i)
      #pragma unroll
      for (int j = 0; j < 4; ++j) acc[i][j] = mfma16(a[i], bb[j], acc[i][j]);
  }
  #pragma unroll
  for (int j = 0; j < 4; ++j) {
    const int gn = n0 + wc * 64 + j * 16 + lr;
    const float bv = bo[gn];
    #pragma unroll
    for (int i = 0; i < 4; ++i) {
      #pragma unroll
      for (int r = 0; r < 4; ++r) {
        const int gm = m0 + wr * 64 + i * 16 + lg * 4 + r;
        out[((size_t)gm << 10) + gn] = acc[i][j][r] + bv;
      }
    }
  }
}

// ---------------- host launch ----------------------------------------------
extern "C" void kernel_launch(void* const* d_in, const int* in_sizes, int n_in,
                              void* d_out, int out_size, void* d_ws, size_t ws_size,
                              hipStream_t stream) {
  const float* q  = (const float*)d_in[0];
  const float* k  = (const float*)d_in[1];
  const float* v  = (const float*)d_in[2];
  const int*  mask = (const int*)d_in[3];
  const float* Wq = (const float*)d_in[4];
  const float* bq = (const float*)d_in[5];
  const float* Wk = (const float*)d_in[6];
  const float* bk = (const float*)d_in[7];
  const float* Wv = (const float*)d_in[8];
  const float* bv = (const float*)d_in[9];
  const float* Wo = (const float*)d_in[10];
  const float* bo = (const float*)d_in[11];

  char* ws = (char*)d_ws;
  unsigned short* wqt  = (unsigned short*)(ws + 0);          // 2 MB
  unsigned short* wkt  = (unsigned short*)(ws + 2097152);    // 2 MB
  unsigned short* wot  = (unsigned short*)(ws + 4194304);    // 128 KB
  unsigned*       mb   = (unsigned*)      (ws + 4325376);    // 512 KB
  unsigned short* qhb  = (unsigned short*)(ws + 4849664);    // 8 MB
  unsigned short* khb  = (unsigned short*)(ws + 13238272);   // 8 MB
  unsigned short* vpt  = (unsigned short*)(ws + 21626880);   // 512 KB
  float*          linv = (float*)         (ws + 22151168);   // 256 KB
  float*          ctxp = (float*)         (ws + 22413312);   // 16 MB -> ends 39190528
  unsigned short* ctxr = (unsigned short*)(ws + 39190528);   // 512 KB -> ends 39702528
  // aliases inside ctxp region (dead at time of use):
  unsigned short* wvt  = (unsigned short*)(ws + 22413312);             // 128 KB, dead after vproj_mm
  float*          ctxvp= (float*)         (ws + 22413312 + 131072);    // 8 MB, dead after vred
  float*          lpart16 = (float*)      (ws + 22413312);             // 4 MB, dead before pass2

  float* out  = (float*)d_out;
  float* attn = out + (size_t)BB * SS * DD;  // 4,194,304

  const float qScale = 0.125f * 1.44269504088896340736f;  // fold log2(e) for exp2

  imha_prep<<<3072, 256, 0, stream>>>(Wq, Wk, Wo, Wv, mask, wqt, wkt, wot, wvt, mb);
  imha_vproj_mm<<<dim3(64, 8), 256, 0, stream>>>(v, wvt, ctxvp);
  imha_vred<<<32, 256, 0, stream>>>(ctxvp, bv, vpt);
  imha_proj2<<<dim3(64, 8, 2), 256, 0, stream>>>(q, k, wqt, wkt, bq, bk, qhb, khb, qScale);
  imha_pass1<<<512, 256, 0, stream>>>(qhb, khb, mb, lpart16);
  imha_linv<<<256, 256, 0, stream>>>(lpart16, linv);
  imha_pass2<<<512, 256, 0, stream>>>(qhb, khb, vpt, mb, linv, attn, ctxp);
  imha_ctxred<<<256, 256, 0, stream>>>(ctxp, ctxr);
  imha_outproj<<<dim3(32, 8), 256, 0, stream>>>(ctxr, wot, bo, out);
}